// Round 5
// baseline (108.929 us; speedup 1.0000x reference)
//
#include <hip/hip_runtime.h>
#include <type_traits>
#include <stdint.h>

#define DEV __device__ __forceinline__

typedef float f32x4 __attribute__((ext_vector_type(4)));
typedef short bf16x8 __attribute__((ext_vector_type(8)));
typedef unsigned short u16;
typedef u16 u16x4 __attribute__((ext_vector_type(4)));

static constexpr int BTOT = 65536;
static constexpr int KB   = 64;
static constexpr int NCHT = BTOT / KB;      // 1024 total chunks
static constexpr int NG   = 56;             // true GEMM pairs
static constexpr int NCOLSUM = 45;
static constexpr float INVB = 1.0f / (float)BTOT;

// 64 chunk-windows of 16 chunks. Per window: 4 GEMM blocks (one per column)
// + 4 R blocks (4 chunks each). grid bx = u*64 + g -> all 8 units of window g
// land on XCD g%8 (round-robin heuristic) for cross-column L2 reuse.
static constexpr int NWIN   = 64;
static constexpr int NBLK_C = 64;           // blocks per GEMM column
static constexpr int NBLK_R = 256;          // 4 per window
static constexpr int GRID   = 8*NWIN;       // 512

struct Col {
  int nslot, np, nsplit, nb;
  int8_t sexp[10][6];          // slot exps over (s1,y1,s2,y2,x1,x2)
  int8_t pa[16], pb[16];       // pair -> slot indices
  int16_t gout[16];            // pair -> global G slot
  uint8_t ldmask;              // which arrays to load
};

struct Tables {
  int nW, nB, nM, nA, nX;
  int8_t expw[120][7];
  int8_t expb[20][3];
  int8_t expm[56][5];
  int8_t am[35][4];            // 4-var monos (s1,y1,s2,y2), product order
  int8_t xm[10][2];            // 2-var monos, product order
  Col col[4];
  // combine-kernel term tables
  int8_t wtype[120]; int16_t widx[120]; int8_t wpow[120]; // 0:GEMM 1:colA[o] 2:colX[d]
  int8_t mtype[56];  int16_t midx[56];  int8_t mpow[56];  // 0:GEMM 1:colA[o] 2:colA[d]
  int16_t bcol[20];  int8_t bpow[20];
  int err, gcount;
};

constexpr int aidf(const Tables& t,int a,int b,int c,int d){
  for(int i=0;i<t.nA;i++)
    if(t.am[i][0]==a&&t.am[i][1]==b&&t.am[i][2]==c&&t.am[i][3]==d) return i;
  return -1;
}
constexpr int xidf(const Tables& t,int a,int b){
  for(int i=0;i<t.nX;i++) if(t.xm[i][0]==a&&t.xm[i][1]==b) return i;
  return -1;
}

constexpr Tables makeTables(){
  Tables t{};
  t.err = 0;
  // EXP_W (python product order)
  t.nW=0;
  for(int e0=0;e0<4;e0++)for(int e1=0;e1<4;e1++)for(int e2=0;e2<4;e2++)
  for(int e3=0;e3<4;e3++)for(int e4=0;e4<4;e4++)for(int e5=0;e5<4;e5++)
  for(int e6=0;e6<4;e6++) if(e0+e1+e2+e3+e4+e5+e6<=3){
    t.expw[t.nW][0]=(int8_t)e0; t.expw[t.nW][1]=(int8_t)e1; t.expw[t.nW][2]=(int8_t)e2;
    t.expw[t.nW][3]=(int8_t)e3; t.expw[t.nW][4]=(int8_t)e4; t.expw[t.nW][5]=(int8_t)e5;
    t.expw[t.nW][6]=(int8_t)e6; t.nW++;
  }
  t.nB=0;
  for(int e0=0;e0<4;e0++)for(int e1=0;e1<4;e1++)for(int e2=0;e2<4;e2++)
    if(e0+e1+e2<=3){ t.expb[t.nB][0]=(int8_t)e0; t.expb[t.nB][1]=(int8_t)e1; t.expb[t.nB][2]=(int8_t)e2; t.nB++; }
  t.nM=0;
  for(int e0=0;e0<4;e0++)for(int e1=0;e1<4;e1++)for(int e2=0;e2<4;e2++)
  for(int e3=0;e3<4;e3++)for(int e4=0;e4<4;e4++)
    if(e0+e1+e2+e3+e4<=3){
      t.expm[t.nM][0]=(int8_t)e0; t.expm[t.nM][1]=(int8_t)e1; t.expm[t.nM][2]=(int8_t)e2;
      t.expm[t.nM][3]=(int8_t)e3; t.expm[t.nM][4]=(int8_t)e4; t.nM++;
    }
  t.nA=0;
  for(int a=0;a<4;a++)for(int b=0;b<4;b++)for(int c=0;c<4;c++)for(int d=0;d<4;d++)
    if(a+b+c+d<=3){ t.am[t.nA][0]=(int8_t)a; t.am[t.nA][1]=(int8_t)b; t.am[t.nA][2]=(int8_t)c; t.am[t.nA][3]=(int8_t)d; t.nA++; }
  t.nX=0;
  for(int a=0;a<4;a++)for(int b=0;b<4;b++)
    if(a+b<=3){ t.xm[t.nX][0]=(int8_t)a; t.xm[t.nX][1]=(int8_t)b; t.nX++; }

  int wslot[35][10]; int mslot[10][10];
  for(int i=0;i<35;i++)for(int j=0;j<10;j++) wslot[i][j]=-1;
  for(int i=0;i<10;i++)for(int j=0;j<10;j++) mslot[i][j]=-1;

  int slot=0;

  // --- Col 0: M (y-monos of (y1,y2), shared A/B slot set) ---
  {
    Col& c = t.col[0]; c.nslot=5; c.nsplit=1; c.nb=NBLK_C;
    int ye[5][2] = {{0,1},{1,0},{0,2},{1,1},{2,0}};   // (y1e,y2e)
    int xmid[5] = {0,0,0,0,0};
    for(int s=0;s<5;s++){
      c.sexp[s][0]=0; c.sexp[s][1]=(int8_t)ye[s][0]; c.sexp[s][2]=0;
      c.sexp[s][3]=(int8_t)ye[s][1]; c.sexp[s][4]=0; c.sexp[s][5]=0;
      xmid[s]=xidf(t, ye[s][0], ye[s][1]);
      if(xmid[s]<0) t.err+=1;
    }
    int p=0;
    for(int L=0;L<2;L++)for(int R=0;R<5;R++){
      c.pa[p]=(int8_t)L; c.pb[p]=(int8_t)R; c.gout[p]=(int16_t)slot;
      mslot[xmid[L]][xmid[R]]=slot; slot++; p++;
    }
    for(int L=2;L<5;L++)for(int R=0;R<2;R++){
      c.pa[p]=(int8_t)L; c.pb[p]=(int8_t)R; c.gout[p]=(int16_t)slot;
      mslot[xmid[L]][xmid[R]]=slot; slot++; p++;
    }
    c.np=p;
    if(p!=16) t.err+=1;
  }
  // --- Col 1/2: W1 (s1,y1) and W2 (s2,y2) ---
  for(int wc=0; wc<2; wc++){
    Col& c = t.col[1+wc]; c.nslot=10; c.nsplit=1; c.nb=NBLK_C;
    int ae[5][2] = {{1,0},{0,1},{2,0},{1,1},{0,2}};
    int xe[5][2] = {{0,1},{1,0},{0,2},{1,1},{2,0}};
    int amid[5]={0,0,0,0,0}, xmidb[5]={0,0,0,0,0};
    for(int s=0;s<5;s++){
      for(int q=0;q<6;q++) c.sexp[s][q]=0;
      if(wc==0){ c.sexp[s][0]=(int8_t)ae[s][0]; c.sexp[s][1]=(int8_t)ae[s][1];
                 amid[s]=aidf(t, ae[s][0], ae[s][1], 0, 0); }
      else     { c.sexp[s][2]=(int8_t)ae[s][0]; c.sexp[s][3]=(int8_t)ae[s][1];
                 amid[s]=aidf(t, 0, 0, ae[s][0], ae[s][1]); }
      if(amid[s]<0) t.err+=1;
      for(int q=0;q<6;q++) c.sexp[5+s][q]=0;
      c.sexp[5+s][4]=(int8_t)xe[s][0]; c.sexp[5+s][5]=(int8_t)xe[s][1];
      xmidb[s]=xidf(t, xe[s][0], xe[s][1]);
      if(xmidb[s]<0) t.err+=1;
    }
    int p=0;
    for(int a=0;a<2;a++)for(int b=0;b<5;b++){
      c.pa[p]=(int8_t)a; c.pb[p]=(int8_t)(5+b); c.gout[p]=(int16_t)slot;
      wslot[amid[a]][xmidb[b]]=slot; slot++; p++;
    }
    for(int a=2;a<5;a++)for(int b=0;b<2;b++){
      c.pa[p]=(int8_t)a; c.pb[p]=(int8_t)(5+b); c.gout[p]=(int16_t)slot;
      wslot[amid[a]][xmidb[b]]=slot; slot++; p++;
    }
    c.np=p;
    if(p!=16) t.err+=1;
  }
  // --- Col 3: W3 (mixed deg-2 v's x deg-1 u's), N-split 2 ---
  {
    Col& c = t.col[3]; c.nslot=6; c.nsplit=2; c.nb=NBLK_C;
    int ae4[4][4] = {{1,0,1,0},{1,0,0,1},{0,1,1,0},{0,1,0,1}};
    int xe[2][2] = {{0,1},{1,0}};
    int amid[4]={0,0,0,0}, xmidb[2]={0,0};
    for(int s=0;s<4;s++){
      c.sexp[s][0]=(int8_t)ae4[s][0]; c.sexp[s][1]=(int8_t)ae4[s][1];
      c.sexp[s][2]=(int8_t)ae4[s][2]; c.sexp[s][3]=(int8_t)ae4[s][3];
      c.sexp[s][4]=0; c.sexp[s][5]=0;
      amid[s]=aidf(t, ae4[s][0], ae4[s][1], ae4[s][2], ae4[s][3]);
      if(amid[s]<0) t.err+=1;
    }
    for(int s=0;s<2;s++){
      for(int q=0;q<6;q++) c.sexp[4+s][q]=0;
      c.sexp[4+s][4]=(int8_t)xe[s][0]; c.sexp[4+s][5]=(int8_t)xe[s][1];
      xmidb[s]=xidf(t, xe[s][0], xe[s][1]);
      if(xmidb[s]<0) t.err+=1;
    }
    int p=0;
    for(int a=0;a<4;a++)for(int b=0;b<2;b++){
      c.pa[p]=(int8_t)a; c.pb[p]=(int8_t)(4+b); c.gout[p]=(int16_t)slot;
      wslot[amid[a]][xmidb[b]]=slot; slot++; p++;
    }
    c.np=p;
    if(p!=8) t.err+=1;
  }
  t.gcount=slot;
  if(slot!=NG) t.err+=1;

  // ldmask from slot exps
  for(int ci=0; ci<4; ci++){
    unsigned m=0;
    for(int s=0;s<t.col[ci].nslot;s++)
      for(int v=0;v<6;v++) if(t.col[ci].sexp[s][v]>0) m |= (1u<<v);
    t.col[ci].ldmask=(uint8_t)m;
  }

  // --- combine tables ---
  for(int i=0;i<t.nW;i++){
    const int8_t* e=t.expw[i];
    bool u0=(e[0]==0&&e[3]==0);
    bool v0=(e[1]==0&&e[2]==0&&e[4]==0&&e[5]==0);
    t.wpow[i]=e[6];
    if(u0){ t.wtype[i]=1; t.widx[i]=(int16_t)aidf(t,e[1],e[2],e[4],e[5]); }
    else if(v0){ t.wtype[i]=2; t.widx[i]=(int16_t)xidf(t,e[0],e[3]); }
    else {
      int s=wslot[aidf(t,e[1],e[2],e[4],e[5])][xidf(t,e[0],e[3])];
      if(s<0) t.err+=1;
      t.wtype[i]=0; t.widx[i]=(int16_t)s;
    }
  }
  for(int i=0;i<t.nM;i++){
    const int8_t* e=t.expm[i];
    bool L0=(e[1]==0&&e[3]==0), R0=(e[0]==0&&e[2]==0);
    t.mpow[i]=e[4];
    if(L0){ t.mtype[i]=2; t.midx[i]=(int16_t)aidf(t,0,e[0],0,e[2]); }
    else if(R0){ t.mtype[i]=1; t.midx[i]=(int16_t)aidf(t,0,e[1],0,e[3]); }
    else {
      int s=mslot[xidf(t,e[1],e[3])][xidf(t,e[0],e[2])];
      if(s<0) t.err+=1;
      t.mtype[i]=0; t.midx[i]=(int16_t)s;
    }
  }
  for(int i=0;i<t.nB;i++){
    const int8_t* e=t.expb[i];
    t.bcol[i]=(int16_t)aidf(t,0,e[0],0,e[1]); t.bpow[i]=e[2];
  }
  return t;
}

constexpr Tables TB = makeTables();
static_assert(TB.err==0 && TB.gcount==56, "table build failed");
static_assert(TB.nW==120 && TB.nB==20 && TB.nM==56 && TB.nA==35 && TB.nX==10, "enumeration mismatch");

// ---- helpers ----
template<int N, typename F>
DEV void sunroll(F&& f){
  if constexpr (N > 0){
    sunroll<N-1>(static_cast<F&&>(f));
    f(std::integral_constant<int, N-1>{});
  }
}
template<int E> DEV float ipw(float x){
  if constexpr(E==0) return 1.0f;
  else if constexpr(E==1) return x;
  else if constexpr(E==2) return x*x;
  else return x*x*x;
}
DEV u16 f2bf(float f){
  uint32_t u = __builtin_bit_cast(uint32_t, f);
  u = u + 0x7FFFu + ((u>>16)&1u);
  return (u16)(u>>16);
}

// Fragment-major LDS layout.
// Element (b in [0,64), ch in [0,64)) of a slot lives at (u16 index):
//   slot*4096 + ((sb*4 + t)*64 + lane)*8 + j
//   where sb=b>>5, t=ch>>4, lane=((b>>3)&3)*16 + (ch&15), j=b&7.
// MFMA fragment semantics: lane l elem j <-> k=(l>>4)*8+j, m/n=l&15  => one ds_read_b128.
DEV bf16x8 readFrag(const u16* lds, int slot, int sb, int t, int l){
  return *(const bf16x8*)&lds[slot*4096 + ((sb*4 + t)*64 + l)*8];
}

// ---- GEMM column: 16 waves, reg-prefetch pipelined chunk loop, raw barriers ----
template<int CI>
DEV void colGemm(const float* __restrict__ s1,const float* __restrict__ y1,
                 const float* __restrict__ s2,const float* __restrict__ y2,
                 const float* __restrict__ x1,const float* __restrict__ x2,
                 float* __restrict__ G, u16* lds, int tid, int bi)
{
  constexpr int NS  = TB.col[CI].nslot;
  constexpr int NSP = TB.col[CI].nsplit;
  constexpr int NDB = 4/NSP;
  constexpr int NB  = TB.col[CI].nb;
  constexpr unsigned LM = TB.col[CI].ldmask;

  const int l=tid&63, ob=(tid>>6)&3, sub=tid>>8, w=tid>>6;
  const int q = (l>>4)&3;
  const int ch = ob*16 + (l&15);
  const int bl = sub*16 + q*4;
  // staging write target (fragment-major): thread's 4 consecutive b at fixed ch
  // -> sbw=sub>>1, lane_w=((sub&1)*2+(q>>1))*16+(ch&15), j base=(q&1)*4
  const int wbase = ((( (sub>>1)*4 + ob)*64) + ((sub&1)*2 + (q>>1))*16 + (l&15))*8 + (q&1)*4;

  int aslot=0,bslot=0,gsl=0,dbase=0;
  sunroll<16>([&](auto W){
    constexpr int ww = decltype(W)::value;
    if(w==ww){
      constexpr int p = ww/NSP;
      aslot = TB.col[CI].pa[p];
      bslot = TB.col[CI].pb[p];
      gsl   = TB.col[CI].gout[p];
      dbase = (ww%NSP)*2;
    }
  });

  const int c0 = (bi*NCHT)/NB, c1 = ((bi+1)*NCHT)/NB;
  f32x4 acc[4][NDB] = {};

  float raw[6][4] = {};
  float nraw[6][4] = {};

  auto issue = [&](int ck, float (&dst)[6][4]){
    const int b0 = (ck*KB + bl)*64 + ch;
    #pragma unroll
    for(int j=0;j<4;j++){
      const int off = b0 + j*64;
      if constexpr(LM&1u)  dst[0][j]=s1[off];
      if constexpr(LM&2u)  dst[1][j]=y1[off];
      if constexpr(LM&4u)  dst[2][j]=s2[off];
      if constexpr(LM&8u)  dst[3][j]=y2[off];
      if constexpr(LM&16u) dst[4][j]=x1[off];
      if constexpr(LM&32u) dst[5][j]=x2[off];
    }
  };

  issue(c0, raw);                       // prologue load

  for(int ck=c0; ck<c1; ++ck){
    // prefetch next chunk into regs (stays in flight across both barriers)
    const int nk = (ck+1<c1)? ck+1 : c0;
    issue(nk, nraw);

    // stage monomials of current chunk
    sunroll<NS>([&](auto S){
      constexpr int s = decltype(S)::value;
      u16x4 o4;
      #pragma unroll
      for(int j=0;j<4;j++){
        float v = ipw<TB.col[CI].sexp[s][0]>(raw[0][j])
                * ipw<TB.col[CI].sexp[s][1]>(raw[1][j])
                * ipw<TB.col[CI].sexp[s][2]>(raw[2][j])
                * ipw<TB.col[CI].sexp[s][3]>(raw[3][j])
                * ipw<TB.col[CI].sexp[s][4]>(raw[4][j])
                * ipw<TB.col[CI].sexp[s][5]>(raw[5][j]);
        o4[j]=f2bf(v);
      }
      *(u16x4*)&lds[s*4096 + wbase] = o4;
    });

    // barrier 1: ds_writes visible; do NOT drain vmcnt
    asm volatile("s_waitcnt lgkmcnt(0)" ::: "memory");
    __builtin_amdgcn_s_barrier();
    __builtin_amdgcn_sched_barrier(0);

    #pragma unroll
    for(int sb=0; sb<2; ++sb){
      bf16x8 Af[4];
      #pragma unroll
      for(int o2=0;o2<4;o2++) Af[o2]=readFrag(lds,aslot,sb,o2,l);
      #pragma unroll
      for(int dd=0;dd<NDB;dd++){
        bf16x8 Bf=readFrag(lds,bslot,sb,dbase+dd,l);
        #pragma unroll
        for(int o2=0;o2<4;o2++)
          acc[o2][dd]=__builtin_amdgcn_mfma_f32_16x16x32_bf16(Af[o2],Bf,acc[o2][dd],0,0,0);
      }
    }

    // barrier 2: reads consumed before next staging overwrites LDS
    __builtin_amdgcn_sched_barrier(0);
    __builtin_amdgcn_s_barrier();
    __builtin_amdgcn_sched_barrier(0);

    #pragma unroll
    for(int a=0;a<6;a++)
      #pragma unroll
      for(int j=0;j<4;j++) raw[a][j]=nraw[a][j];
  }

  float* dst = G + gsl*4096;
  const int r0=(l>>4)*4, cc=l&15;   // C/D layout: col=lane&15, row=(lane>>4)*4+reg
  #pragma unroll
  for(int o2=0;o2<4;o2++)
    #pragma unroll
    for(int dd=0;dd<NDB;dd++)
      #pragma unroll
      for(int r=0;r<4;r++)
        atomicAdd(&dst[(o2*16+r0+r)*64 + (dbase+dd)*16+cc], acc[o2][dd][r]);
}

// ---- reduction column: all 45 colsums in fp32 ----
DEV void colRed(const float* __restrict__ s1,const float* __restrict__ y1,
                const float* __restrict__ s2,const float* __restrict__ y2,
                const float* __restrict__ x1,const float* __restrict__ x2,
                float* __restrict__ col, float* ldsF, int tid, int bi)
{
  const int ch=tid&63, g=tid>>6;
  const int c0=(bi*NCHT)/NBLK_R, c1=((bi+1)*NCHT)/NBLK_R;
  float accv[45];
  sunroll<45>([&](auto K){ accv[decltype(K)::value]=0.f; });
  for(int r=c0*KB+g; r<c1*KB; r+=16){
    const int off=r*64+ch;
    const float v0=s1[off],v1=y1[off],v2=s2[off],v3=y2[off],v4=x1[off],v5=x2[off];
    sunroll<35>([&](auto K){
      constexpr int k=decltype(K)::value;
      accv[k] += ipw<TB.am[k][0]>(v0)*ipw<TB.am[k][1]>(v1)*ipw<TB.am[k][2]>(v2)*ipw<TB.am[k][3]>(v3);
    });
    sunroll<10>([&](auto K){
      constexpr int k=decltype(K)::value;
      accv[35+k] += ipw<TB.xm[k][0]>(v4)*ipw<TB.xm[k][1]>(v5);
    });
  }
  sunroll<5>([&](auto RR){
    constexpr int rr=decltype(RR)::value;
    __syncthreads();
    sunroll<9>([&](auto Q){
      constexpr int q=decltype(Q)::value;
      ldsF[(q*16+g)*64+ch]=accv[rr*9+q];
    });
    __syncthreads();
    if(tid<576){
      const int q=tid>>6, c=tid&63;
      float s=0.f;
      #pragma unroll
      for(int gg=0; gg<16; gg++) s+=ldsF[(q*16+gg)*64+c];
      atomicAdd(&col[(rr*9+q)*64+c], s);
    }
  });
}

__global__ __launch_bounds__(1024) void k_main(
    const float* __restrict__ x1, const float* __restrict__ s1, const float* __restrict__ y1,
    const float* __restrict__ x2, const float* __restrict__ s2, const float* __restrict__ y2,
    float* __restrict__ G, float* __restrict__ col)
{
  __shared__ u16 lds[10*4096];   // 80 KiB -> 2 blocks/CU
  const int tid = threadIdx.x;
  const int u = blockIdx.x >> 6;     // unit within window
  const int g = blockIdx.x & 63;     // chunk-window (XCD = g%8)
  if      (u==0) colGemm<0>(s1,y1,s2,y2,x1,x2,G,lds,tid,g);
  else if (u==1) colGemm<1>(s1,y1,s2,y2,x1,x2,G,lds,tid,g);
  else if (u==2) colGemm<2>(s1,y1,s2,y2,x1,x2,G,lds,tid,g);
  else if (u==3) colGemm<3>(s1,y1,s2,y2,x1,x2,G,lds,tid,g);
  else           colRed(s1,y1,s2,y2,x1,x2,col,(float*)lds,tid, g*4 + (u-4));
}

__global__ __launch_bounds__(256) void k_combine(
    const float* __restrict__ G, const float* __restrict__ col,
    const float* __restrict__ w, const float* __restrict__ b, const float* __restrict__ m,
    const float* __restrict__ parw, const float* __restrict__ parb, const float* __restrict__ parm,
    float* __restrict__ out)
{
  const int n = blockIdx.x*256 + threadIdx.x;   // 0..4095
  const int o = n>>6, d = n&63;
  const float wv = w[n], mv = m[n];
  const float wp[4] = {1.f, wv, wv*wv, wv*wv*wv};
  const float mp[4] = {1.f, mv, mv*mv, mv*mv*mv};
  float aw=0.f, am=0.f;
  sunroll<120>([&](auto II){
    constexpr int i = decltype(II)::value;
    constexpr int ty = TB.wtype[i];
    constexpr int ix = TB.widx[i];
    constexpr int q  = TB.wpow[i];
    float val;
    if constexpr(ty==0) val = G[ix*4096 + n];
    else if constexpr(ty==1) val = col[ix*64 + o];
    else val = col[(35+ix)*64 + d];
    aw += parw[i] * val * wp[q];
  });
  sunroll<56>([&](auto II){
    constexpr int i = decltype(II)::value;
    constexpr int ty = TB.mtype[i];
    constexpr int ix = TB.midx[i];
    constexpr int q  = TB.mpow[i];
    float val;
    if constexpr(ty==0) val = G[ix*4096 + n];
    else if constexpr(ty==1) val = col[ix*64 + o];
    else val = col[ix*64 + d];
    am += parm[i] * val * mp[q];
  });
  aw *= INVB; am *= INVB;
  if (o==d) am += parm[56];
  out[n] = aw;
  out[4160 + n] = am;
  if (n < 64){
    const float bv = b[n];
    const float bp[4] = {1.f, bv, bv*bv, bv*bv*bv};
    float ab=0.f;
    sunroll<20>([&](auto II){
      constexpr int i = decltype(II)::value;
      constexpr int cix = TB.bcol[i];
      constexpr int q = TB.bpow[i];
      ab += parb[i] * col[cix*64 + n] * bp[q];
    });
    out[4096 + n] = ab * INVB;
  }
}

extern "C" void kernel_launch(void* const* d_in, const int* in_sizes, int n_in,
                              void* d_out, int out_size, void* d_ws, size_t ws_size,
                              hipStream_t stream)
{
  const float* x1=(const float*)d_in[0];
  const float* s1=(const float*)d_in[1];
  const float* y1=(const float*)d_in[2];
  const float* x2=(const float*)d_in[3];
  const float* s2=(const float*)d_in[4];
  const float* y2=(const float*)d_in[5];
  const float* w =(const float*)d_in[6];
  const float* b =(const float*)d_in[7];
  const float* m =(const float*)d_in[8];
  const float* parw=(const float*)d_in[9];
  const float* parb=(const float*)d_in[10];
  const float* parm=(const float*)d_in[11];

  float* G   = (float*)d_ws;
  float* col = G + NG*4096;

  hipMemsetAsync(d_ws, 0, (size_t)(NG*4096 + NCOLSUM*64)*sizeof(float), stream);
  k_main<<<GRID, 1024, 0, stream>>>(x1,s1,y1,x2,s2,y2,G,col);
  k_combine<<<16, 256, 0, stream>>>(G,col,w,b,m,parw,parb,parm,(float*)d_out);
}